// Round 1
// baseline (6462.454 us; speedup 1.0000x reference)
//
#include <hip/hip_runtime.h>
#include <stdint.h>

// RNN_29102698398007 — B=64, T=512, D=H=1024.  Inputs fp32, output fp32.
//
//   gemm_xh : xh = X @ Kw -> Y fp32 (in place of output)          [1 launch]
//   swz     : W_rec fp32 -> d_ws bf16, MFMA B-frag order; zero bar [1 launch]
//   scan_k  : ALL 512 steps in ONE persistent kernel.             [1 launch]
//             64 wgs x 256 thr; W_rec resident in VGPRs (128/wave);
//             h broadcast via double-buffered bf16 buffer in d_ws;
//             device-scope monotonic-counter barrier between steps.
// Fallback (ws too small): old per-step launch path retained.

using short8 = __attribute__((ext_vector_type(8))) short;
using bf16x8 = __attribute__((ext_vector_type(8))) __bf16;
using f32x4  = __attribute__((ext_vector_type(4))) float;

typedef unsigned short u16;
typedef unsigned int   u32;

#define T_  512
#define H_  1024
#define NWG 64

__device__ __forceinline__ u16 f2bf(float f) {
    union { float f; u32 i; } v; v.f = f;
    u32 b = v.i + 0x7fffu + ((v.i >> 16) & 1u);   // RNE; finite values only
    return (u16)(b >> 16);
}
__device__ __forceinline__ f32x4 mfma_bf16_16x16x32(short8 a, short8 b, f32x4 c) {
    return __builtin_amdgcn_mfma_f32_16x16x32_bf16(
        __builtin_bit_cast(bf16x8, a), __builtin_bit_cast(bf16x8, b), c, 0, 0, 0);
}
__device__ __forceinline__ float sigmoidf(float z) {
    z = fminf(fmaxf(z, -30.f), 30.f);
    return 1.f / (1.f + __expf(-z));
}
__device__ __forceinline__ short8 cvt8(f32x4 a0, f32x4 a1) {
    short8 r;
    #pragma unroll
    for (int j = 0; j < 4; ++j) { r[j] = (short)f2bf(a0[j]); r[4 + j] = (short)f2bf(a1[j]); }
    return r;
}

// ---------------- k0: xh = X[32768,1024] @ Kw[1024,1024], fp32 -> fp32 ----------------
__global__ __launch_bounds__(256) void gemm_xh(const float* __restrict__ X,
                                               const float* __restrict__ Kw,
                                               float* __restrict__ Y)
{
    __shared__ alignas(16) u16 Bt[64][40];     // [n][k], k padded 32->40
    const int tid  = threadIdx.x;
    const int lane = tid & 63;
    const int wv   = tid >> 6;
    const int quad = lane >> 4;
    const int l16  = lane & 15;
    const int m0   = blockIdx.x * 64;
    const int n0   = blockIdx.y * 64;
    const int cB   = tid & 63;                 // staging: n within tile
    const int kg   = tid >> 6;                 // staging: k octet

    f32x4 acc[4] = {};

    for (int k0 = 0; k0 < H_; k0 += 32) {
        __syncthreads();
        short8 sv;
        #pragma unroll
        for (int jj = 0; jj < 8; ++jj)
            sv[jj] = (short)f2bf(Kw[(k0 + kg * 8 + jj) * H_ + n0 + cB]);
        *(short8*)&Bt[cB][kg * 8] = sv;
        __syncthreads();

        const f32x4* p = (const f32x4*)&X[(m0 + wv * 16 + l16) * H_ + k0 + quad * 8];
        short8 av = cvt8(p[0], p[1]);
        #pragma unroll
        for (int nt = 0; nt < 4; ++nt) {
            short8 bv = *(const short8*)&Bt[nt * 16 + l16][quad * 8];
            acc[nt] = mfma_bf16_16x16x32(av, bv, acc[nt]);
        }
    }
    #pragma unroll
    for (int nt = 0; nt < 4; ++nt)
        #pragma unroll
        for (int r = 0; r < 4; ++r)
            Y[(m0 + wv * 16 + quad * 4 + r) * H_ + n0 + nt * 16 + l16] = acc[nt][r];
}

// ---------------- k1: swizzle W_rec (fp32) into bf16 B-frag order; zero barrier ----------------
__global__ __launch_bounds__(256) void swz(const float* __restrict__ Kr,
                                           u16* __restrict__ Wsw,
                                           u32* __restrict__ cnt)
{
    const int t    = blockIdx.x * 256 + threadIdx.x;   // [0, 131072)
    if (t == 0 && cnt) *cnt = 0;                       // reset grid barrier each replay
    const int lane = t & 63;
    const int kt   = (t >> 6) & 31;
    const int wv   = (t >> 11) & 1;
    const int gj   = t >> 12;
    const int quad = lane >> 4;
    const int l16  = lane & 15;
    const int col  = gj * 32 + wv * 16 + l16;
    short8 sv;
    #pragma unroll
    for (int jj = 0; jj < 8; ++jj)
        sv[jj] = (short)f2bf(Kr[(kt * 32 + quad * 8 + jj) * H_ + col]);
    *(short8*)&Wsw[t * 8] = sv;
}

// ---------------- k2 (new): persistent scan — all 512 steps, one launch ----------------
// 64 wgs x 256 thr. wg g16 owns cols [16*g16, 16*g16+16) for ALL 64 batch rows.
// Wave wv computes rows [16*wv, 16*wv+16). W-frags live in 128 VGPRs/wave.
// h_s kept as bf16 in hb[ s&1 ][64][1024]; cross-step sync = monotonic barrier.
__global__ __launch_bounds__(256, 1) void scan_k(float* __restrict__ Y,
                                                 const u16* __restrict__ Wsw,
                                                 u16* __restrict__ hb,
                                                 u32* __restrict__ cnt)
{
    const int tid  = threadIdx.x;
    const int lane = tid & 63;
    const int wv   = tid >> 6;
    const int quad = lane >> 4;
    const int l16  = lane & 15;
    const int g16  = blockIdx.x;            // [0,64): 16-col group
    const int c0   = g16 * 16;

    // --- load W fragments into registers: 32 x short8 = 128 VGPRs ---
    short8 wf[32];
    #pragma unroll
    for (int j2 = 0; j2 < 32; ++j2)
        wf[j2] = *(const short8*)&Wsw[(((unsigned)g16 * 32 + (unsigned)j2) * 64 + (unsigned)lane) * 8];

    const int arow = wv * 16 + l16;         // A-frag row (batch index)
    u16* const hb0 = hb;
    u16* const hb1 = hb + 64 * H_;

    for (int s = 0; s < T_; ++s) {
        // prefetch xh for this step (independent of h_{s-1}; overlaps MFMA chain)
        float xh[4];
        #pragma unroll
        for (int r = 0; r < 4; ++r) {
            const int row = wv * 16 + quad * 4 + r;
            xh[r] = Y[((size_t)row * T_ + (size_t)s) * H_ + c0 + l16];
        }

        f32x4 a0 = {}, a1 = {};
        if (s > 0) {
            const u16* hp = ((s - 1) & 1) ? hb1 : hb0;      // h_{s-1}
            const u16* ap = hp + arow * H_ + quad * 8;
            #pragma unroll
            for (int j2 = 0; j2 < 32; ++j2) {
                short8 av = *(const short8*)(ap + j2 * 32);
                if (j2 & 1) a1 = mfma_bf16_16x16x32(av, wf[j2], a1);
                else        a0 = mfma_bf16_16x16x32(av, wf[j2], a0);
            }
        }

        u16* const hc = (s & 1) ? hb1 : hb0;                // h_s
        #pragma unroll
        for (int r = 0; r < 4; ++r) {
            const int row = wv * 16 + quad * 4 + r;
            const size_t idx = ((size_t)row * T_ + (size_t)s) * H_ + c0 + l16;
            const float h = sigmoidf(a0[r] + a1[r] + xh[r]);
            Y[idx] = h;                                     // fp32 output
            hc[row * H_ + c0 + l16] = f2bf(h);              // bf16 broadcast copy
        }

        if (s + 1 < T_) {
            __syncthreads();                                // wg stores drained to L2
            if (tid == 0) {
                __threadfence();                            // agent release (wb L2)
                __hip_atomic_fetch_add(cnt, 1u, __ATOMIC_RELEASE, __HIP_MEMORY_SCOPE_AGENT);
                const u32 tgt = (u32)(s + 1) * (u32)NWG;
                while (__hip_atomic_load(cnt, __ATOMIC_ACQUIRE, __HIP_MEMORY_SCOPE_AGENT) < tgt) {
                    __builtin_amdgcn_s_sleep(1);
                }
            }
            __syncthreads();                                // acquire propagates to wg
        }
    }
}

// ---------------- k2 (fallback): one scan step per launch ----------------
template<bool SW>
__global__ __launch_bounds__(128) void step_k(float* __restrict__ Y,
                                              const void* __restrict__ Wsrc,
                                              int s)
{
    const int tid  = threadIdx.x;
    const int lane = tid & 63;
    const int wv   = tid >> 6;
    const int quad = lane >> 4;
    const int l16  = lane & 15;
    const int gi   = blockIdx.x >> 5;
    const int gj   = blockIdx.x & 31;
    const int colBase = gj * 32 + wv * 16;

    f32x4 acc = {};
    if (s > 0) {
        const int abase = ((gi * 16 + l16) * T_ + (s - 1)) * H_;
        #pragma unroll 4
        for (int j2 = 0; j2 < 32; ++j2) {
            const f32x4* ap = (const f32x4*)&Y[abase + j2 * 32 + quad * 8];
            short8 av = cvt8(ap[0], ap[1]);
            short8 bv;
            if (SW) {
                bv = *(const short8*)&((const u16*)Wsrc)[(((gj * 2 + wv) * 32 + j2) * 64 + lane) * 8];
            } else {
                const float* Krf = (const float*)Wsrc;
                #pragma unroll
                for (int jj = 0; jj < 8; ++jj)
                    bv[jj] = (short)f2bf(Krf[(j2 * 32 + quad * 8 + jj) * H_ + colBase + l16]);
            }
            acc = mfma_bf16_16x16x32(av, bv, acc);
        }
    }
    #pragma unroll
    for (int r = 0; r < 4; ++r) {
        const int idx = ((gi * 16 + quad * 4 + r) * T_ + s) * H_ + colBase + l16;
        float z = acc[r] + Y[idx];
        Y[idx] = sigmoidf(z);
    }
}

extern "C" void kernel_launch(void* const* d_in, const int* in_sizes, int n_in,
                              void* d_out, int out_size, void* d_ws, size_t ws_size,
                              hipStream_t stream) {
    const float* X  = (const float*)d_in[0];   // x [64,512,1024] fp32
    const float* Kw = (const float*)d_in[1];   // kernel [1024,1024] fp32
    const float* Kr = (const float*)d_in[2];   // recurrent_kernel [1024,1024] fp32
    float* Y        = (float*)d_out;           // [64,512,1024] fp32 (xh, then h)

    gemm_xh<<<dim3(512, 16), dim3(256), 0, stream>>>(X, Kw, Y);

    // d_ws layout: [0,2MB) Wsw bf16 | [2MB,2MB+256KB) h double-buffer | +256KB barrier
    const size_t WSW_B  = (size_t)2 * 1024 * 1024;
    const size_t HB_B   = (size_t)2 * 64 * H_ * sizeof(u16);   // 256 KB
    const size_t needed = WSW_B + HB_B + 64;

    if (ws_size >= needed) {
        u16* Wsw = (u16*)d_ws;
        u16* hbd = (u16*)((char*)d_ws + WSW_B);
        u32* cnt = (u32*)((char*)d_ws + WSW_B + HB_B);
        swz<<<dim3(512), dim3(256), 0, stream>>>(Kr, Wsw, cnt);
        scan_k<<<dim3(NWG), dim3(256), 0, stream>>>(Y, Wsw, hbd, cnt);
    } else if (ws_size >= WSW_B) {
        u16* Wsw = (u16*)d_ws;
        swz<<<dim3(512), dim3(256), 0, stream>>>(Kr, Wsw, (u32*)nullptr);
        for (int s = 0; s < T_; ++s)
            step_k<true><<<dim3(128), dim3(128), 0, stream>>>(Y, (const void*)Wsw, s);
    } else {
        for (int s = 0; s < T_; ++s)
            step_k<false><<<dim3(128), dim3(128), 0, stream>>>(Y, (const void*)Kr, s);
    }
}

// Round 2
// 5545.529 us; speedup vs baseline: 1.1653x; 1.1653x over previous
//
#include <hip/hip_runtime.h>
#include <stdint.h>

// RNN_29102698398007 — B=64, T=512, D=H=1024.  Inputs fp32, output fp32.
//
//   gemm_xh : xh = X @ Kw -> Y fp32 (in place of output)           [1 launch]
//   swz     : W_rec fp32 -> d_ws bf16 frag order; zero 4 barriers  [1 launch]
//   scan_k  : ALL 512 steps in ONE persistent kernel.              [1 launch]
//     V2: 32 wgs x 512 thr = 4 row-groups x 8 col-groups.
//         Each row-group (16 batch rows) has a PRIVATE barrier (8 arrivals,
//         own cache line) -> 8x less atomic serialization than r1's 64-arrival
//         single counter, and independent row-group pipelines absorb skew.
//         W_rec register-resident (128 VGPR/wave). h as bf16 double buffer.
//         Y store + next xh prefetch overlapped into the spin window.
// Fallback (ws too small): per-step launch path retained.

using short8 = __attribute__((ext_vector_type(8))) short;
using bf16x8 = __attribute__((ext_vector_type(8))) __bf16;
using f32x4  = __attribute__((ext_vector_type(4))) float;

typedef unsigned short u16;
typedef unsigned int   u32;

#define T_  512
#define H_  1024
#define RG_ARR 8      // wgs arriving per row-group barrier

__device__ __forceinline__ u16 f2bf(float f) {
    union { float f; u32 i; } v; v.f = f;
    u32 b = v.i + 0x7fffu + ((v.i >> 16) & 1u);   // RNE; finite values only
    return (u16)(b >> 16);
}
__device__ __forceinline__ f32x4 mfma_bf16_16x16x32(short8 a, short8 b, f32x4 c) {
    return __builtin_amdgcn_mfma_f32_16x16x32_bf16(
        __builtin_bit_cast(bf16x8, a), __builtin_bit_cast(bf16x8, b), c, 0, 0, 0);
}
__device__ __forceinline__ float sigmoidf(float z) {
    z = fminf(fmaxf(z, -30.f), 30.f);
    return 1.f / (1.f + __expf(-z));
}
__device__ __forceinline__ short8 cvt8(f32x4 a0, f32x4 a1) {
    short8 r;
    #pragma unroll
    for (int j = 0; j < 4; ++j) { r[j] = (short)f2bf(a0[j]); r[4 + j] = (short)f2bf(a1[j]); }
    return r;
}

// ---------------- k0: xh = X[32768,1024] @ Kw[1024,1024], fp32 -> fp32 ----------------
__global__ __launch_bounds__(256) void gemm_xh(const float* __restrict__ X,
                                               const float* __restrict__ Kw,
                                               float* __restrict__ Y)
{
    __shared__ alignas(16) u16 Bt[64][40];     // [n][k], k padded 32->40
    const int tid  = threadIdx.x;
    const int lane = tid & 63;
    const int wv   = tid >> 6;
    const int quad = lane >> 4;
    const int l16  = lane & 15;
    const int m0   = blockIdx.x * 64;
    const int n0   = blockIdx.y * 64;
    const int cB   = tid & 63;                 // staging: n within tile
    const int kg   = tid >> 6;                 // staging: k octet

    f32x4 acc[4] = {};

    for (int k0 = 0; k0 < H_; k0 += 32) {
        __syncthreads();
        short8 sv;
        #pragma unroll
        for (int jj = 0; jj < 8; ++jj)
            sv[jj] = (short)f2bf(Kw[(k0 + kg * 8 + jj) * H_ + n0 + cB]);
        *(short8*)&Bt[cB][kg * 8] = sv;
        __syncthreads();

        const f32x4* p = (const f32x4*)&X[(m0 + wv * 16 + l16) * H_ + k0 + quad * 8];
        short8 av = cvt8(p[0], p[1]);
        #pragma unroll
        for (int nt = 0; nt < 4; ++nt) {
            short8 bv = *(const short8*)&Bt[nt * 16 + l16][quad * 8];
            acc[nt] = mfma_bf16_16x16x32(av, bv, acc[nt]);
        }
    }
    #pragma unroll
    for (int nt = 0; nt < 4; ++nt)
        #pragma unroll
        for (int r = 0; r < 4; ++r)
            Y[(m0 + wv * 16 + quad * 4 + r) * H_ + n0 + nt * 16 + l16] = acc[nt][r];
}

// ---------------- k1: swizzle W_rec (fp32) into bf16 B-frag order; zero barriers --------
// Wsw frag layout: [(c16*32 + kt)*64 + lane]*8, c16 = 16-col group [0,64)
__global__ __launch_bounds__(256) void swz(const float* __restrict__ Kr,
                                           u16* __restrict__ Wsw,
                                           u32* __restrict__ cnt)
{
    const int t    = blockIdx.x * 256 + threadIdx.x;   // [0, 131072)
    if (cnt && t < 4) cnt[t * 64] = 0;                 // reset 4 row-group barriers
    const int lane = t & 63;
    const int kt   = (t >> 6) & 31;
    const int wv   = (t >> 11) & 1;
    const int gj   = t >> 12;
    const int quad = lane >> 4;
    const int l16  = lane & 15;
    const int col  = gj * 32 + wv * 16 + l16;
    short8 sv;
    #pragma unroll
    for (int jj = 0; jj < 8; ++jj)
        sv[jj] = (short)f2bf(Kr[(kt * 32 + quad * 8 + jj) * H_ + col]);
    *(short8*)&Wsw[t * 8] = sv;
}

// ---------------- k2 (new): persistent scan — 4 row-groups x 8 col-groups ----------------
// wg(rg,cg): rows [16rg,16rg+16) x cols [128cg,128cg+128). 8 waves, 16 cols/wave.
// Barrier per row-group: counter at cnt[rg*64] (256B apart), 8 arrivals, monotonic.
__global__ __launch_bounds__(512, 2) void scan_k(float* __restrict__ Y,
                                                 const u16* __restrict__ Wsw,
                                                 u16* __restrict__ hb,
                                                 u32* __restrict__ cnt)
{
    const int tid  = threadIdx.x;
    const int lane = tid & 63;
    const int wv   = tid >> 6;          // 0..7
    const int quad = lane >> 4;
    const int l16  = lane & 15;
    const int rg   = blockIdx.x >> 3;   // 0..3  row-group
    const int cg   = blockIdx.x & 7;    // 0..7  col-group
    const int col  = cg * 128 + wv * 16 + l16;   // this lane's output column
    const int c16  = cg * 8 + wv;       // 16-col group id [0,64)

    // --- W fragments resident: 32 x short8 = 128 VGPRs/wave ---
    short8 wf[32];
    #pragma unroll
    for (int j2 = 0; j2 < 32; ++j2)
        wf[j2] = *(const short8*)&Wsw[(((unsigned)c16 * 32 + (unsigned)j2) * 64 + (unsigned)lane) * 8];

    u32* const bar = cnt + rg * 64;     // private, 256B-spaced counter
    u16* const hb0 = hb;
    u16* const hb1 = hb + 64 * H_;
    const int arow = rg * 16 + l16;     // A-frag batch row

    // prefetch xh for s=0
    float xh[4];
    #pragma unroll
    for (int r = 0; r < 4; ++r) {
        const int row = rg * 16 + quad * 4 + r;
        xh[r] = Y[((size_t)row * T_) * H_ + col];
    }

    for (int s = 0; s < T_; ++s) {
        f32x4 a0 = {}, a1 = {};
        if (s > 0) {
            const u16* hp = ((s - 1) & 1) ? hb1 : hb0;          // h_{s-1}
            const u16* ap = hp + (size_t)arow * H_ + quad * 8;
            #pragma unroll
            for (int j2 = 0; j2 < 32; ++j2) {
                short8 av = *(const short8*)(ap + j2 * 32);
                if (j2 & 1) a1 = mfma_bf16_16x16x32(av, wf[j2], a1);
                else        a0 = mfma_bf16_16x16x32(av, wf[j2], a0);
            }
        }

        u16* const hc = (s & 1) ? hb1 : hb0;                    // h_s
        float hv[4];
        #pragma unroll
        for (int r = 0; r < 4; ++r) {
            const int row = rg * 16 + quad * 4 + r;
            hv[r] = sigmoidf(a0[r] + a1[r] + xh[r]);
            hc[row * H_ + col] = f2bf(hv[r]);                   // bf16 broadcast copy
        }

        if (s + 1 < T_) {
            __syncthreads();            // all wg hb stores drained to L2
            if (tid == 0) {
                __threadfence();        // agent release: wb L2 -> IC
                __hip_atomic_fetch_add(bar, 1u, __ATOMIC_RELAXED, __HIP_MEMORY_SCOPE_AGENT);
            }
            // overlapped with barrier wait: fp32 Y store + next xh prefetch
            #pragma unroll
            for (int r = 0; r < 4; ++r) {
                const int row = rg * 16 + quad * 4 + r;
                Y[((size_t)row * T_ + s) * H_ + col] = hv[r];
                xh[r] = Y[((size_t)row * T_ + (s + 1)) * H_ + col];
            }
            if (tid == 0) {
                const u32 tgt = (u32)(s + 1) * (u32)RG_ARR;
                // relaxed polling (no cache-wide inv per poll)
                while (__hip_atomic_load(bar, __ATOMIC_RELAXED, __HIP_MEMORY_SCOPE_AGENT) < tgt)
                    __builtin_amdgcn_s_sleep(1);
                // single acquire (inv) to publish peers' hb stores; kept live
                if (__hip_atomic_load(bar, __ATOMIC_ACQUIRE, __HIP_MEMORY_SCOPE_AGENT) < tgt)
                    __builtin_amdgcn_s_sleep(1);
            }
            __syncthreads();
        } else {
            #pragma unroll
            for (int r = 0; r < 4; ++r) {
                const int row = rg * 16 + quad * 4 + r;
                Y[((size_t)row * T_ + s) * H_ + col] = hv[r];
            }
        }
    }
}

// ---------------- k2 (fallback): one scan step per launch ----------------
template<bool SW>
__global__ __launch_bounds__(128) void step_k(float* __restrict__ Y,
                                              const void* __restrict__ Wsrc,
                                              int s)
{
    const int tid  = threadIdx.x;
    const int lane = tid & 63;
    const int wv   = tid >> 6;
    const int quad = lane >> 4;
    const int l16  = lane & 15;
    const int gi   = blockIdx.x >> 5;
    const int gj   = blockIdx.x & 31;
    const int colBase = gj * 32 + wv * 16;

    f32x4 acc = {};
    if (s > 0) {
        const int abase = ((gi * 16 + l16) * T_ + (s - 1)) * H_;
        #pragma unroll 4
        for (int j2 = 0; j2 < 32; ++j2) {
            const f32x4* ap = (const f32x4*)&Y[abase + j2 * 32 + quad * 8];
            short8 av = cvt8(ap[0], ap[1]);
            short8 bv;
            if (SW) {
                bv = *(const short8*)&((const u16*)Wsrc)[(((gj * 2 + wv) * 32 + j2) * 64 + lane) * 8];
            } else {
                const float* Krf = (const float*)Wsrc;
                #pragma unroll
                for (int jj = 0; jj < 8; ++jj)
                    bv[jj] = (short)f2bf(Krf[(j2 * 32 + quad * 8 + jj) * H_ + colBase + l16]);
            }
            acc = mfma_bf16_16x16x32(av, bv, acc);
        }
    }
    #pragma unroll
    for (int r = 0; r < 4; ++r) {
        const int idx = ((gi * 16 + quad * 4 + r) * T_ + s) * H_ + colBase + l16;
        float z = acc[r] + Y[idx];
        Y[idx] = sigmoidf(z);
    }
}

extern "C" void kernel_launch(void* const* d_in, const int* in_sizes, int n_in,
                              void* d_out, int out_size, void* d_ws, size_t ws_size,
                              hipStream_t stream) {
    const float* X  = (const float*)d_in[0];   // x [64,512,1024] fp32
    const float* Kw = (const float*)d_in[1];   // kernel [1024,1024] fp32
    const float* Kr = (const float*)d_in[2];   // recurrent_kernel [1024,1024] fp32
    float* Y        = (float*)d_out;           // [64,512,1024] fp32 (xh, then h)

    gemm_xh<<<dim3(512, 16), dim3(256), 0, stream>>>(X, Kw, Y);

    // d_ws: [0,2MB) Wsw | [2MB,+256KB) h double buffer | then 4 counters 256B apart
    const size_t WSW_B  = (size_t)2 * 1024 * 1024;
    const size_t HB_B   = (size_t)2 * 64 * H_ * sizeof(u16);   // 256 KB
    const size_t needed = WSW_B + HB_B + 1024;

    if (ws_size >= needed) {
        u16* Wsw = (u16*)d_ws;
        u16* hbd = (u16*)((char*)d_ws + WSW_B);
        u32* cnt = (u32*)((char*)d_ws + WSW_B + HB_B);
        swz<<<dim3(512), dim3(256), 0, stream>>>(Kr, Wsw, cnt);
        scan_k<<<dim3(32), dim3(512), 0, stream>>>(Y, Wsw, hbd, cnt);
    } else if (ws_size >= WSW_B) {
        u16* Wsw = (u16*)d_ws;
        swz<<<dim3(512), dim3(256), 0, stream>>>(Kr, Wsw, (u32*)nullptr);
        for (int s = 0; s < T_; ++s)
            step_k<true><<<dim3(128), dim3(128), 0, stream>>>(Y, (const void*)Wsw, s);
    } else {
        for (int s = 0; s < T_; ++s)
            step_k<false><<<dim3(128), dim3(128), 0, stream>>>(Y, (const void*)Kr, s);
    }
}

// Round 3
// 3110.413 us; speedup vs baseline: 2.0777x; 1.7829x over previous
//
#include <hip/hip_runtime.h>
#include <stdint.h>

// RNN_29102698398007 — B=64, T=512, D=H=1024.  Inputs fp32, output fp32.
//
//   gemm_xh : xh = X @ Kw -> Y fp32 (in place of output)           [1 launch]
//   swz     : W_rec fp32 -> d_ws bf16 frag order; zero 4 barriers  [1 launch]
//   scan_k  : ALL 512 steps in ONE persistent kernel.              [1 launch]
//     V3: 32 wgs x 512 thr = 4 row-groups x 8 col-groups, as V2, but:
//       * NO cache-wide release fence (V2's __threadfence -> buffer_wbl2 was
//         the suspected dominant per-step cost).  h hand-off data is written
//         with relaxed AGENT-scope atomic u64 stores (sc0 sc1 write-through to
//         MALL; vmcnt retires at coherence point), so a relaxed arrival add
//         after vmcnt(0)+syncthreads is a valid release.  Y stores stay dirty
//         in local L2 and are never flushed mid-kernel.
//       * MFMA operands SWAPPED: acc = mfma(wf, h_frag, acc) gives D with
//         lane = (outcol quad*4+r, batchrow l16) -> one u64 (4 bf16) h store
//         per lane, placed directly in A/B-frag order so next step reads are
//         one contiguous 16B load per lane per k-chunk.
//       * 4 accumulators (deeper MFMA dep chain).
// Fallback (ws too small): per-step launch path retained.

using short8 = __attribute__((ext_vector_type(8))) short;
using bf16x8 = __attribute__((ext_vector_type(8))) __bf16;
using f32x4  = __attribute__((ext_vector_type(4))) float;

typedef unsigned short     u16;
typedef unsigned int       u32;
typedef unsigned long long u64;

#define T_  512
#define H_  1024
#define RG_ARR 8      // wgs arriving per row-group barrier

__device__ __forceinline__ u16 f2bf(float f) {
    union { float f; u32 i; } v; v.f = f;
    u32 b = v.i + 0x7fffu + ((v.i >> 16) & 1u);   // RNE; finite values only
    return (u16)(b >> 16);
}
__device__ __forceinline__ f32x4 mfma_bf16_16x16x32(short8 a, short8 b, f32x4 c) {
    return __builtin_amdgcn_mfma_f32_16x16x32_bf16(
        __builtin_bit_cast(bf16x8, a), __builtin_bit_cast(bf16x8, b), c, 0, 0, 0);
}
__device__ __forceinline__ float sigmoidf(float z) {
    z = fminf(fmaxf(z, -30.f), 30.f);
    return 1.f / (1.f + __expf(-z));
}
__device__ __forceinline__ short8 cvt8(f32x4 a0, f32x4 a1) {
    short8 r;
    #pragma unroll
    for (int j = 0; j < 4; ++j) { r[j] = (short)f2bf(a0[j]); r[4 + j] = (short)f2bf(a1[j]); }
    return r;
}

// ---------------- k0: xh = X[32768,1024] @ Kw[1024,1024], fp32 -> fp32 ----------------
__global__ __launch_bounds__(256) void gemm_xh(const float* __restrict__ X,
                                               const float* __restrict__ Kw,
                                               float* __restrict__ Y)
{
    __shared__ alignas(16) u16 Bt[64][40];     // [n][k], k padded 32->40
    const int tid  = threadIdx.x;
    const int lane = tid & 63;
    const int wv   = tid >> 6;
    const int quad = lane >> 4;
    const int l16  = lane & 15;
    const int m0   = blockIdx.x * 64;
    const int n0   = blockIdx.y * 64;
    const int cB   = tid & 63;                 // staging: n within tile
    const int kg   = tid >> 6;                 // staging: k octet

    f32x4 acc[4] = {};

    for (int k0 = 0; k0 < H_; k0 += 32) {
        __syncthreads();
        short8 sv;
        #pragma unroll
        for (int jj = 0; jj < 8; ++jj)
            sv[jj] = (short)f2bf(Kw[(k0 + kg * 8 + jj) * H_ + n0 + cB]);
        *(short8*)&Bt[cB][kg * 8] = sv;
        __syncthreads();

        const f32x4* p = (const f32x4*)&X[(m0 + wv * 16 + l16) * H_ + k0 + quad * 8];
        short8 av = cvt8(p[0], p[1]);
        #pragma unroll
        for (int nt = 0; nt < 4; ++nt) {
            short8 bv = *(const short8*)&Bt[nt * 16 + l16][quad * 8];
            acc[nt] = mfma_bf16_16x16x32(av, bv, acc[nt]);
        }
    }
    #pragma unroll
    for (int nt = 0; nt < 4; ++nt)
        #pragma unroll
        for (int r = 0; r < 4; ++r)
            Y[(m0 + wv * 16 + quad * 4 + r) * H_ + n0 + nt * 16 + l16] = acc[nt][r];
}

// ---------------- k1: swizzle W_rec (fp32) into bf16 B-frag order; zero barriers --------
// Wsw frag layout: [(c16*32 + kt)*64 + lane]*8, c16 = 16-col group [0,64)
__global__ __launch_bounds__(256) void swz(const float* __restrict__ Kr,
                                           u16* __restrict__ Wsw,
                                           u32* __restrict__ cnt)
{
    const int t    = blockIdx.x * 256 + threadIdx.x;   // [0, 131072)
    if (cnt && t < 4) cnt[t * 64] = 0;                 // reset 4 row-group barriers
    const int lane = t & 63;
    const int kt   = (t >> 6) & 31;
    const int wv   = (t >> 11) & 1;
    const int gj   = t >> 12;
    const int quad = lane >> 4;
    const int l16  = lane & 15;
    const int col  = gj * 32 + wv * 16 + l16;
    short8 sv;
    #pragma unroll
    for (int jj = 0; jj < 8; ++jj)
        sv[jj] = (short)f2bf(Kr[(kt * 32 + quad * 8 + jj) * H_ + col]);
    *(short8*)&Wsw[t * 8] = sv;
}

// ---------------- k2 (V3): persistent scan — 4 row-groups x 8 col-groups ----------------
// wg(rg,cg): rows [16rg,16rg+16) x cols [128cg,128cg+128). 8 waves, 16 cols/wave.
// h_s stored per-rg in MFMA frag order: hbF[parity][rg] : 32KB, element (batch b, col C)
// at byte  (C>>5)*1024 + (((C>>3)&3)*16 + b)*16 + (C&7)*2.
__global__ __launch_bounds__(512) void scan_k(float* __restrict__ Y,
                                              const u16* __restrict__ Wsw,
                                              u16* __restrict__ hb,
                                              u32* __restrict__ cnt)
{
    const int tid  = threadIdx.x;
    const int lane = tid & 63;
    const int wv   = tid >> 6;          // 0..7
    const int quad = lane >> 4;
    const int l16  = lane & 15;
    const int rg   = blockIdx.x >> 3;   // 0..3  row-group
    const int cg   = blockIdx.x & 7;    // 0..7  col-group
    const int c16  = cg * 8 + wv;       // 16-col group id [0,64)

    // --- W fragments resident: 32 x short8 = 128 VGPRs/wave ---
    short8 wf[32];
    #pragma unroll
    for (int j2 = 0; j2 < 32; ++j2)
        wf[j2] = *(const short8*)&Wsw[(((unsigned)c16 * 32 + (unsigned)j2) * 64 + (unsigned)lane) * 8];

    u32* const bar = cnt + rg * 64;     // private, 256B-spaced counter

    // frag-order h buffers (u16 elements): parity stride 65536 (128KB), rg stride 16384 (32KB)
    u16* const hbF0 = hb + rg * 16384;
    u16* const hbF1 = hb + 65536 + rg * 16384;

    // writer slot: one u64 (4 bf16, cols C0..C0+3) per lane
    const int C0    = cg * 128 + wv * 16 + quad * 4;
    const int j2w   = C0 >> 5;
    const int quadp = (C0 >> 3) & 3;
    const int half  = (C0 >> 2) & 1;
    const int wOff  = j2w * 512 + (quadp * 16 + l16) * 8 + half * 4;   // u16 units

    // xh / Y address base: row = rg*16 + l16 (batch), cols C0..C0+3 (f32x4)
    const size_t rowBase = ((size_t)(rg * 16 + l16) * T_) * H_ + (size_t)C0;

    f32x4 xh = *(const f32x4*)&Y[rowBase];      // prefetch xh for s=0

    for (int s = 0; s < T_; ++s) {
        f32x4 a0 = {}, a1 = {}, a2 = {}, a3 = {};
        if (s > 0) {
            const u16* hp = ((s - 1) & 1) ? hbF1 : hbF0;
            const u16* ap = hp + lane * 8;       // + j2*512
            #pragma unroll
            for (int j2 = 0; j2 < 32; ++j2) {
                short8 av = *(const short8*)(ap + j2 * 512);
                switch (j2 & 3) {
                    case 0: a0 = mfma_bf16_16x16x32(wf[j2], av, a0); break;
                    case 1: a1 = mfma_bf16_16x16x32(wf[j2], av, a1); break;
                    case 2: a2 = mfma_bf16_16x16x32(wf[j2], av, a2); break;
                    default:a3 = mfma_bf16_16x16x32(wf[j2], av, a3); break;
                }
            }
        }

        f32x4 hv;
        #pragma unroll
        for (int r = 0; r < 4; ++r)
            hv[r] = sigmoidf((a0[r] + a1[r]) + (a2[r] + a3[r]) + xh[r]);

        // device-coherent h store: one relaxed agent-scope u64 (write-through to MALL)
        const u64 pk = (u64)f2bf(hv[0]) | ((u64)f2bf(hv[1]) << 16)
                     | ((u64)f2bf(hv[2]) << 32) | ((u64)f2bf(hv[3]) << 48);
        u16* const hc = (s & 1) ? hbF1 : hbF0;
        __hip_atomic_store((u64*)(hc + wOff), pk, __ATOMIC_RELAXED, __HIP_MEMORY_SCOPE_AGENT);

        if (s + 1 < T_) {
            asm volatile("s_waitcnt vmcnt(0)" ::: "memory");  // h store at coherence point
            __syncthreads();                                  // whole wg's h stores done
            if (tid == 0)                                     // release: data already coherent
                __hip_atomic_fetch_add(bar, 1u, __ATOMIC_RELAXED, __HIP_MEMORY_SCOPE_AGENT);
            // overlapped with peers' arrival/poll: fp32 Y store + next xh prefetch
            *(f32x4*)&Y[rowBase + (size_t)s * H_] = hv;
            xh = *(const f32x4*)&Y[rowBase + (size_t)(s + 1) * H_];
            if (tid == 0) {
                const u32 tgt = (u32)(s + 1) * (u32)RG_ARR;
                while (__hip_atomic_load(bar, __ATOMIC_RELAXED, __HIP_MEMORY_SCOPE_AGENT) < tgt)
                    __builtin_amdgcn_s_sleep(1);
                // single acquire (inv L1+L2) so normal loads below refetch from MALL
                if (__hip_atomic_load(bar, __ATOMIC_ACQUIRE, __HIP_MEMORY_SCOPE_AGENT) < tgt)
                    __builtin_amdgcn_s_sleep(1);
            }
            __syncthreads();
        } else {
            *(f32x4*)&Y[rowBase + (size_t)s * H_] = hv;
        }
    }
}

// ---------------- k2 (fallback): one scan step per launch ----------------
template<bool SW>
__global__ __launch_bounds__(128) void step_k(float* __restrict__ Y,
                                              const void* __restrict__ Wsrc,
                                              int s)
{
    const int tid  = threadIdx.x;
    const int lane = tid & 63;
    const int wv   = tid >> 6;
    const int quad = lane >> 4;
    const int l16  = lane & 15;
    const int gi   = blockIdx.x >> 5;
    const int gj   = blockIdx.x & 31;
    const int colBase = gj * 32 + wv * 16;

    f32x4 acc = {};
    if (s > 0) {
        const int abase = ((gi * 16 + l16) * T_ + (s - 1)) * H_;
        #pragma unroll 4
        for (int j2 = 0; j2 < 32; ++j2) {
            const f32x4* ap = (const f32x4*)&Y[abase + j2 * 32 + quad * 8];
            short8 av = cvt8(ap[0], ap[1]);
            short8 bv;
            if (SW) {
                bv = *(const short8*)&((const u16*)Wsrc)[(((gj * 2 + wv) * 32 + j2) * 64 + lane) * 8];
            } else {
                const float* Krf = (const float*)Wsrc;
                #pragma unroll
                for (int jj = 0; jj < 8; ++jj)
                    bv[jj] = (short)f2bf(Krf[(j2 * 32 + quad * 8 + jj) * H_ + colBase + l16]);
            }
            acc = mfma_bf16_16x16x32(av, bv, acc);
        }
    }
    #pragma unroll
    for (int r = 0; r < 4; ++r) {
        const int idx = ((gi * 16 + quad * 4 + r) * T_ + s) * H_ + colBase + l16;
        float z = acc[r] + Y[idx];
        Y[idx] = sigmoidf(z);
    }
}

extern "C" void kernel_launch(void* const* d_in, const int* in_sizes, int n_in,
                              void* d_out, int out_size, void* d_ws, size_t ws_size,
                              hipStream_t stream) {
    const float* X  = (const float*)d_in[0];   // x [64,512,1024] fp32
    const float* Kw = (const float*)d_in[1];   // kernel [1024,1024] fp32
    const float* Kr = (const float*)d_in[2];   // recurrent_kernel [1024,1024] fp32
    float* Y        = (float*)d_out;           // [64,512,1024] fp32 (xh, then h)

    gemm_xh<<<dim3(512, 16), dim3(256), 0, stream>>>(X, Kw, Y);

    // d_ws: [0,2MB) Wsw | [2MB,+256KB) h frag double buffer | then 4 counters 256B apart
    const size_t WSW_B  = (size_t)2 * 1024 * 1024;
    const size_t HB_B   = (size_t)2 * 64 * H_ * sizeof(u16);   // 256 KB
    const size_t needed = WSW_B + HB_B + 1024;

    if (ws_size >= needed) {
        u16* Wsw = (u16*)d_ws;
        u16* hbd = (u16*)((char*)d_ws + WSW_B);
        u32* cnt = (u32*)((char*)d_ws + WSW_B + HB_B);
        swz<<<dim3(512), dim3(256), 0, stream>>>(Kr, Wsw, cnt);
        scan_k<<<dim3(32), dim3(512), 0, stream>>>(Y, Wsw, hbd, cnt);
    } else if (ws_size >= WSW_B) {
        u16* Wsw = (u16*)d_ws;
        swz<<<dim3(512), dim3(256), 0, stream>>>(Kr, Wsw, (u32*)nullptr);
        for (int s = 0; s < T_; ++s)
            step_k<true><<<dim3(128), dim3(128), 0, stream>>>(Y, (const void*)Wsw, s);
    } else {
        for (int s = 0; s < T_; ++s)
            step_k<false><<<dim3(128), dim3(128), 0, stream>>>(Y, (const void*)Kr, s);
    }
}